// Round 12
// baseline (844.244 us; speedup 1.0000x reference)
//
#include <hip/hip_runtime.h>
#include <hip/hip_bf16.h>
#include <hip/hip_cooperative_groups.h>

namespace cg = cooperative_groups;

typedef __hip_bfloat16 bf16;
typedef __attribute__((ext_vector_type(8))) short short8;
typedef __attribute__((ext_vector_type(4))) short shortx4;
typedef __attribute__((ext_vector_type(4))) float floatx4;

#define BATCH   2
#define SEQ     1024
#define DIM     1024
#define D_INNER 2048
#define D_STATE 16
#define DT_RANK 64
#define MROWS   (BATCH * SEQ)   // 2048
#define CHUNK   32
#define NCHUNK  (SEQ / CHUNK)   // 32

__device__ __forceinline__ float bf2f(bf16 x) { return __bfloat162float(x); }
__device__ __forceinline__ bf16  f2bf(float x) { return __float2bfloat16(x); }
__device__ __forceinline__ short bfbits(float x) {
    bf16 b = __float2bfloat16(x); short s; __builtin_memcpy(&s, &b, 2); return s;
}

// async global->LDS, 16B per lane (wave-uniform base + lane*16; m104/m108).
__device__ __forceinline__ void ld_lds16(const void* g, void* l) {
    __builtin_amdgcn_global_load_lds(
        (const __attribute__((address_space(1))) void*)g,
        (__attribute__((address_space(3))) void*)l, 16, 0, 0);
}

// ---------------------------------------------------------------------------
// fp32 -> bf16 casts (4 elem/thread); cast2_k fuses two tensors in one grid.
// ---------------------------------------------------------------------------
__device__ __forceinline__ void cast4(const float* in, short* o, int i) {
    floatx4 v = ((const floatx4*)in)[i];
    shortx4 r;
    r.x = bfbits(v.x); r.y = bfbits(v.y); r.z = bfbits(v.z); r.w = bfbits(v.w);
    ((shortx4*)o)[i] = r;
}
__global__ __launch_bounds__(256) void cast_k(
    const float* __restrict__ in, short* __restrict__ o, int n4)
{
    int i = blockIdx.x * 256 + threadIdx.x;
    if (i < n4) cast4(in, o, i);
}
__global__ __launch_bounds__(256) void cast2_k(
    const float* __restrict__ a, short* __restrict__ oa, int na4,
    const float* __restrict__ b, short* __restrict__ ob, int nb4)
{
    int i = blockIdx.x * 256 + threadIdx.x;
    if (i < na4) cast4(a, oa, i);
    else if (i - na4 < nb4) cast4(b, ob, i - na4);
}

// 8 contiguous elements -> short8 bf16 (fp32 converted on the fly).
__device__ __forceinline__ short8 ld8_any(const void* p, size_t eoff, int is_f32) {
    if (is_f32) {
        const float* f = (const float*)p + eoff;
        floatx4 a = *(const floatx4*)f;
        floatx4 b = *(const floatx4*)(f + 4);
        short8 r;
        r[0] = bfbits(a[0]); r[1] = bfbits(a[1]); r[2] = bfbits(a[2]); r[3] = bfbits(a[3]);
        r[4] = bfbits(b[0]); r[5] = bfbits(b[1]); r[6] = bfbits(b[2]); r[7] = bfbits(b[3]);
        return r;
    } else {
        return *(const short8*)((const bf16*)p + eoff);
    }
}

// ---------------------------------------------------------------------------
// gemm128: C[m,n] = sum_k A[m,k]*B[n,k]; 128x128x32 tile, 4 waves (2x2),
// global_load_lds width=16 staging, split-K via blockIdx.z.
// R12: XOR-swizzled LDS layout — row r's k-chunk c stored at chunk position
// c ^ s(r), s(r)=(r&3)^((r>>2)&3). DMA pattern unchanged (staging lanes fetch
// a permuted global column); quad frag reads go 8-way -> 2-way bank aliasing
// (2-way is free, m136). R9 evidence: 1.05M SQ_LDS_BANK_CONFLICT cycles.
// ---------------------------------------------------------------------------
__global__ __launch_bounds__(256) void gemm128(
    const bf16* __restrict__ A, int lda,
    const bf16* __restrict__ B, int ldb,
    float* __restrict__ Cf, bf16* __restrict__ Cb, int ldc,
    int kchunk, size_t psize)
{
    __shared__ short As[128 * 32];
    __shared__ short Bs[128 * 32];
    const int tid  = threadIdx.x;
    const int wave = tid >> 6;
    const int lane = tid & 63;
    const int m0 = blockIdx.y * 128;
    const int n0 = blockIdx.x * 128;
    const int wm = (wave & 1) * 64;
    const int wn = (wave >> 1) * 64;
    const int r16  = lane & 15;
    const int quad = lane >> 4;
    const int r0 = tid >> 2;                              // staging row 0..63
    const int sw = (r0 & 3) ^ ((r0 >> 2) & 3);            // same for r0+64
    const int c0 = (((tid & 3) ^ sw) << 3);               // swizzled global col
    const int kbeg = blockIdx.z * kchunk;

    floatx4 acc[4][4] = {};

    for (int k0 = kbeg; k0 < kbeg + kchunk; k0 += 32) {
        __syncthreads();
        ld_lds16(A + (size_t)(m0 + r0) * lda + k0 + c0,      As + tid * 8);
        ld_lds16(A + (size_t)(m0 + r0 + 64) * lda + k0 + c0, As + (tid + 256) * 8);
        ld_lds16(B + (size_t)(n0 + r0) * ldb + k0 + c0,      Bs + tid * 8);
        ld_lds16(B + (size_t)(n0 + r0 + 64) * ldb + k0 + c0, Bs + (tid + 256) * 8);
        __syncthreads();
        short8 af[4], bg[4];
#pragma unroll
        for (int i = 0; i < 4; i++) {
            int Ra = wm + i * 16 + r16;
            int Rb = wn + i * 16 + r16;
            int sa = (Ra & 3) ^ ((Ra >> 2) & 3);
            int sb = (Rb & 3) ^ ((Rb >> 2) & 3);
            af[i] = *(const short8*)(As + Ra * 32 + ((quad ^ sa) << 3));
            bg[i] = *(const short8*)(Bs + Rb * 32 + ((quad ^ sb) << 3));
        }
#pragma unroll
        for (int i = 0; i < 4; i++)
#pragma unroll
            for (int j = 0; j < 4; j++)
                acc[i][j] = __builtin_amdgcn_mfma_f32_16x16x32_bf16(af[i], bg[j], acc[i][j], 0, 0, 0);
    }

    float* Cfp = Cf ? Cf + (size_t)blockIdx.z * psize : nullptr;
#pragma unroll
    for (int i = 0; i < 4; i++)
#pragma unroll
        for (int j = 0; j < 4; j++) {
            int gm = m0 + wm + i * 16 + quad * 4;
            int gn = n0 + wn + j * 16 + r16;
#pragma unroll
            for (int r = 0; r < 4; r++) {
                size_t o = (size_t)(gm + r) * ldc + gn;
                float v = acc[i][j][r];
                if (Cfp) Cfp[o] = v;
                if (Cb) Cb[o] = f2bf(v);
            }
        }
}

// ---------------------------------------------------------------------------
// gemm_bt (64x64x32): for N=96 (x_proj, split-K) and K=64 (dt_proj).
// ---------------------------------------------------------------------------
__global__ __launch_bounds__(256) void gemm_bt(
    const void* __restrict__ A, int a_f32, int lda,
    const void* __restrict__ B, int b_f32, int ldb,
    float* __restrict__ Cf, bf16* __restrict__ Cb, int ldc,
    int N, int K, size_t psize,
    const float* __restrict__ bias, int act)
{
    __shared__ short As[64][40];
    __shared__ short Bs[64][40];
    const int m0   = blockIdx.y * 64;
    const int n0   = blockIdx.x * 64;
    const int tid  = threadIdx.x;
    const int wave = tid >> 6;
    const int lane = tid & 63;
    const int srow = tid >> 2;
    const int scol = (tid & 3) << 3;
    const int r16  = lane & 15;
    const int quad = lane >> 4;
    const int kbeg = blockIdx.z * K;

    floatx4 acc[4] = {};

    for (int k0 = kbeg; k0 < kbeg + K; k0 += 32) {
        short8 av = ld8_any(A, (size_t)(m0 + srow) * lda + k0 + scol, a_f32);
        short8 bv = {};
        int gn = n0 + srow;
        if (gn < N) bv = ld8_any(B, (size_t)gn * ldb + k0 + scol, b_f32);
        *(short8*)(&As[srow][scol]) = av;
        *(short8*)(&Bs[srow][scol]) = bv;
        __syncthreads();
        short8 af = *(const short8*)(&As[wave * 16 + r16][quad * 8]);
#pragma unroll
        for (int nt = 0; nt < 4; nt++) {
            short8 bq = *(const short8*)(&Bs[nt * 16 + r16][quad * 8]);
            acc[nt] = __builtin_amdgcn_mfma_f32_16x16x32_bf16(af, bq, acc[nt], 0, 0, 0);
        }
        __syncthreads();
    }

    float* Cfp = Cf ? Cf + (size_t)blockIdx.z * psize : nullptr;
#pragma unroll
    for (int nt = 0; nt < 4; nt++) {
        int gn = n0 + nt * 16 + r16;
        if (gn >= N) continue;
        float bsv = bias ? bias[gn] : 0.f;
#pragma unroll
        for (int r = 0; r < 4; r++) {
            int gm = m0 + wave * 16 + quad * 4 + r;
            float v = acc[nt][r] + bsv;
            if (act == 1) v = (v > 20.f) ? v : log1pf(__expf(v));  // softplus
            size_t o = (size_t)gm * ldc + gn;
            if (Cfp) Cfp[o] = v;
            if (Cb) Cb[o] = f2bf(v);
        }
    }
}

// sum 8 split-K partials -> fp32
__global__ __launch_bounds__(256) void reduce8_k(
    const float* __restrict__ part, float* __restrict__ o, int n, size_t psize)
{
    int i = blockIdx.x * 256 + threadIdx.x;
    if (i >= n) return;
    float v = 0.f;
#pragma unroll
    for (int j = 0; j < 8; j++) v += part[i + (size_t)j * psize];
    o[i] = v;
}

// sum 2 split-K partials -> fp32 and/or bf16
__global__ __launch_bounds__(256) void reduce2_k(
    const float* __restrict__ part, size_t psize, int n,
    float* __restrict__ of, bf16* __restrict__ ob)
{
    int i = blockIdx.x * 256 + threadIdx.x;
    if (i >= n) return;
    float v = part[i] + part[i + psize];
    if (of) of[i] = v;
    if (ob) ob[i] = f2bf(v);
}

// ---------------------------------------------------------------------------
// Depthwise causal conv (4 taps) + bias + SiLU over xi = xz[:, :, 0:2048].
// ---------------------------------------------------------------------------
__global__ __launch_bounds__(256) void conv_silu_k(
    const bf16* __restrict__ xz, const float* __restrict__ cw,
    const float* __restrict__ cb, bf16* __restrict__ xcb)
{
    int idx = blockIdx.x * 256 + threadIdx.x;      // bt*2048 + d
    int d   = idx & (D_INNER - 1);
    int bt  = idx >> 11;
    int t   = bt & (SEQ - 1);
    float s = cb[d];
#pragma unroll
    for (int j = 0; j < 4; j++) {
        int tt = t - 3 + j;
        if (tt >= 0) s += cw[d * 4 + j] * bf2f(xz[(size_t)(bt - 3 + j) * 4096 + d]);
    }
    float sig = 1.f / (1.f + __expf(-s));
    xcb[idx] = f2bf(s * sig);
}

// ---------------------------------------------------------------------------
// Fused selective scan (R12): single cooperative kernel, 3 phases with
// grid.sync() between. Phase 1: stage dt/xc/B/C into LDS, local chunk scan
// from h=0 -> (S, sum dt) to global. Phase 2: 65536 threads do the 32-chunk
// prefix in-place (cS := h_init). Phase 3: re-scan own chunk FROM THE LDS
// TILES STILL RESIDENT (no re-staging; ~50 MB/layer saved), fused y-dot +
// D*xc + silu(z) gating. Combine order identical to the R11 3-kernel version
// -> bit-identical output. LDS 52 KB -> 2 blocks/CU co-resident (512 blocks).
// ---------------------------------------------------------------------------
__global__ __launch_bounds__(256) void scan_fused_k(
    const float* __restrict__ dtf, const bf16* __restrict__ xcb,
    const float* __restrict__ xdbl, const bf16* __restrict__ xz,
    const float* __restrict__ Alog, const float* __restrict__ Dp,
    float* __restrict__ csdt, float* __restrict__ cS,
    bf16* __restrict__ yb)
{
    __shared__ float dt_s[CHUNK][256];
    __shared__ short xc_s[CHUNK][256];
    __shared__ float B_s[CHUNK][16];
    __shared__ float C_s[CHUNK][16];
    const int tid = threadIdx.x;
    const int d0  = blockIdx.x * 256;
    const int d   = d0 + tid;
    const int b   = blockIdx.y;
    const int c   = blockIdx.z;
    const size_t rbase = (size_t)b * SEQ + c * CHUNK;
    cg::grid_group grid = cg::this_grid();

    // ---- phase 1: stage + local scan ----
#pragma unroll 4
    for (int t = 0; t < CHUNK; t++) {
        dt_s[t][tid] = dtf[(rbase + t) * D_INNER + d0 + tid];
        ((short*)xc_s)[t * 256 + tid] = *(const short*)&xcb[(rbase + t) * D_INNER + d0 + tid];
    }
    for (int e = tid; e < CHUNK * 16; e += 256) {
        int t = e >> 4, n = e & 15;
        B_s[t][n] = xdbl[(rbase + t) * 96 + 64 + n];
        C_s[t][n] = xdbl[(rbase + t) * 96 + 80 + n];
    }
    float A[16];
#pragma unroll
    for (int n = 0; n < 16; n++) A[n] = -__expf(Alog[(size_t)d * 16 + n]);
    float h[16] = {};
    float sdt = 0.f;
    __syncthreads();

    for (int t = 0; t < CHUNK; t++) {
        float dtv = dt_s[t][tid];
        bf16 xcr; short xs = xc_s[t][tid]; __builtin_memcpy(&xcr, &xs, 2);
        float u = dtv * bf2f(xcr);
        sdt += dtv;
        floatx4 B0 = *(const floatx4*)&B_s[t][0];
        floatx4 B1 = *(const floatx4*)&B_s[t][4];
        floatx4 B2 = *(const floatx4*)&B_s[t][8];
        floatx4 B3 = *(const floatx4*)&B_s[t][12];
#pragma unroll
        for (int n = 0; n < 4; n++) {
            h[n]      = __expf(dtv * A[n])      * h[n]      + u * B0[n];
            h[n + 4]  = __expf(dtv * A[n + 4])  * h[n + 4]  + u * B1[n];
            h[n + 8]  = __expf(dtv * A[n + 8])  * h[n + 8]  + u * B2[n];
            h[n + 12] = __expf(dtv * A[n + 12]) * h[n + 12] + u * B3[n];
        }
    }
    csdt[(b * NCHUNK + c) * D_INNER + d] = sdt;
#pragma unroll
    for (int n = 0; n < 16; n++)
        cS[((size_t)(b * NCHUNK + c) * 16 + n) * D_INNER + d] = h[n];
    __threadfence();
    grid.sync();

    // ---- phase 2: in-place prefix over chunks (cS := h_init) ----
    {
        int lb = blockIdx.x + 8 * (blockIdx.y + 2 * blockIdx.z);
        int gid = lb * 256 + tid;
        if (gid < BATCH * D_INNER * D_STATE) {
            int dd = gid & (D_INNER - 1);
            int nn = (gid >> 11) & 15;
            int bb = gid >> 15;
            float Av = -__expf(Alog[(size_t)dd * 16 + nn]);
            float hh = 0.f;
#pragma unroll 4
            for (int j = 0; j < NCHUNK; j++) {
                size_t si = ((size_t)(bb * NCHUNK + j) * 16 + nn) * D_INNER + dd;
                float S  = cS[si];
                float sd = csdt[(bb * NCHUNK + j) * D_INNER + dd];
                cS[si] = hh;
                hh = __expf(sd * Av) * hh + S;
            }
        }
    }
    __threadfence();
    grid.sync();

    // ---- phase 3: re-scan from h_init using resident LDS tiles ----
#pragma unroll
    for (int n = 0; n < 16; n++)
        h[n] = cS[((size_t)(b * NCHUNK + c) * 16 + n) * D_INNER + d];
    const float Dv = Dp[d];

    for (int t = 0; t < CHUNK; t++) {
        size_t row = rbase + t;
        float dtv = dt_s[t][tid];
        bf16 xcr; short xs = xc_s[t][tid]; __builtin_memcpy(&xcr, &xs, 2);
        float xcv = bf2f(xcr);
        float u = dtv * xcv;
        floatx4 B0 = *(const floatx4*)&B_s[t][0];
        floatx4 B1 = *(const floatx4*)&B_s[t][4];
        floatx4 B2 = *(const floatx4*)&B_s[t][8];
        floatx4 B3 = *(const floatx4*)&B_s[t][12];
        floatx4 C0 = *(const floatx4*)&C_s[t][0];
        floatx4 C1 = *(const floatx4*)&C_s[t][4];
        floatx4 C2 = *(const floatx4*)&C_s[t][8];
        floatx4 C3 = *(const floatx4*)&C_s[t][12];
        float y = 0.f;
#pragma unroll
        for (int n = 0; n < 4; n++) {
            h[n]      = __expf(dtv * A[n])      * h[n]      + u * B0[n];
            h[n + 4]  = __expf(dtv * A[n + 4])  * h[n + 4]  + u * B1[n];
            h[n + 8]  = __expf(dtv * A[n + 8])  * h[n + 8]  + u * B2[n];
            h[n + 12] = __expf(dtv * A[n + 12]) * h[n + 12] + u * B3[n];
            y += h[n] * C0[n] + h[n + 4] * C1[n] + h[n + 8] * C2[n] + h[n + 12] * C3[n];
        }
        float zv = bf2f(xz[row * 4096 + 2048 + d]);
        y = (y + Dv * xcv) * (zv / (1.f + __expf(-zv)));
        yb[row * D_INNER + d] = f2bf(y);
    }
}

extern "C" void kernel_launch(void* const* d_in, const int* in_sizes, int n_in,
                              void* d_out, int out_size, void* d_ws, size_t ws_size,
                              hipStream_t stream)
{
    // ALL inputs fp32; OUTPUT IS FP32.
    const float* x    = (const float*)d_in[0];
    const float* inw  = (const float*)d_in[1];
    const float* cw   = (const float*)d_in[2];
    const float* cb   = (const float*)d_in[3];
    const float* xpw  = (const float*)d_in[4];
    const float* dtw  = (const float*)d_in[5];
    const float* dtb  = (const float*)d_in[6];
    const float* Alog = (const float*)d_in[7];
    const float* Dp   = (const float*)d_in[8];
    const float* ow   = (const float*)d_in[9];
    float* out = (float*)d_out;

    // workspace layout (~87 MB)
    char* p = (char*)d_ws;
    bf16*  xzb   = (bf16*)p;  p += (size_t)MROWS * 4096 * 2;        // 16.8 MB
    bf16*  xcb   = (bf16*)p;  p += (size_t)MROWS * D_INNER * 2;     //  8.4 MB
    float* xdblf = (float*)p; p += (size_t)MROWS * 96 * 4;          //  0.8 MB
    float* dtf   = (float*)p; p += (size_t)MROWS * D_INNER * 4;     // 16.8 MB
    bf16*  ybf   = (bf16*)p;  p += (size_t)MROWS * D_INNER * 2;     //  8.4 MB
    bf16*  xmid  = (bf16*)p;  p += (size_t)MROWS * DIM * 2;         //  4.2 MB
    float* csdt  = (float*)p; p += (size_t)BATCH * NCHUNK * D_INNER * 4;      // 0.5 MB
    float* cS    = (float*)p; p += (size_t)BATCH * NCHUNK * 16 * D_INNER * 4; // 8.4 MB
    bf16*  xb    = (bf16*)p;  p += (size_t)MROWS * DIM * 2;         //  4.2 MB
    bf16*  inwb  = (bf16*)p;  p += (size_t)2 * D_INNER * DIM * 2;   //  8.4 MB (one layer)
    bf16*  owb   = (bf16*)p;  p += (size_t)DIM * D_INNER * 2;       //  4.2 MB (one layer)
    float* xprt  = (float*)p; p += (size_t)8 * MROWS * 96 * 4;      //  6.3 MB

    const size_t xp_psize = (size_t)MROWS * 96;
    const size_t op_psize = (size_t)MROWS * DIM;
    float* outp = dtf;   // dtf dead after scans; holds 2 out_proj partials

    // input cast (once)
    cast_k<<<(MROWS * DIM / 4 + 255) / 256, 256, 0, stream>>>(x, (short*)xb, MROWS * DIM / 4);

    for (int l = 0; l < 2; l++) {
        const float* xpw_l = xpw + (size_t)l * 96 * D_INNER;
        const float* dtw_l = dtw + (size_t)l * D_INNER * DT_RANK;
        const float* Al    = Alog + (size_t)l * D_INNER * D_STATE;
        const float* Dpl   = Dp + (size_t)l * D_INNER;

        // 0. cast this layer's big weights to bf16 (fused single dispatch)
        {
            int na4 = 2 * D_INNER * DIM / 4, nb4 = DIM * D_INNER / 4;
            cast2_k<<<(na4 + nb4 + 255) / 256, 256, 0, stream>>>(
                inw + (size_t)l * 2 * D_INNER * DIM, (short*)inwb, na4,
                ow + (size_t)l * DIM * D_INNER, (short*)owb, nb4);
        }

        // 1. xz = xin @ in_proj_w^T   (M=2048, N=4096, K=1024), bf16 out
        gemm128<<<dim3(32, 16, 1), 256, 0, stream>>>(
            (l == 0) ? xb : xmid, DIM, inwb, DIM,
            nullptr, xzb, 4096, DIM, 0);

        // 2. causal depthwise conv + bias + SiLU
        conv_silu_k<<<(MROWS * D_INNER) / 256, 256, 0, stream>>>(
            xzb, cw + (size_t)l * D_INNER * 4, cb + (size_t)l * D_INNER, xcb);

        // 3. x_dbl = xc @ x_proj_w^T   (N=96, K=2048), split-K=8 + reduce
        gemm_bt<<<dim3(2, 32, 8), 256, 0, stream>>>(
            xcb, 0, D_INNER, xpw_l, 1, D_INNER,
            xprt, nullptr, 96, 96, 256, xp_psize, nullptr, 0);
        reduce8_k<<<(MROWS * 96 + 255) / 256, 256, 0, stream>>>(
            xprt, xdblf, MROWS * 96, xp_psize);

        // 4. dt = softplus(dt_raw @ dt_proj_w^T + dt_b)  (N=2048, K=64), fp32
        gemm_bt<<<dim3(32, 32), 256, 0, stream>>>(
            xdblf, 1, 96, dtw_l, 1, DT_RANK,
            dtf, nullptr, D_INNER, D_INNER, DT_RANK, 0,
            dtb + (size_t)l * D_INNER, 1);

        // 5. fused cooperative selective scan (3 phases in one kernel)
        {
            void* args[] = {
                (void*)&dtf, (void*)&xcb, (void*)&xdblf, (void*)&xzb,
                (void*)&Al, (void*)&Dpl, (void*)&csdt, (void*)&cS, (void*)&ybf
            };
            hipLaunchCooperativeKernel((void*)scan_fused_k,
                dim3(D_INNER / 256, BATCH, NCHUNK), dim3(256),
                args, 0, stream);
        }

        // 6. out = y @ out_proj_w^T   (N=1024, K=2048), split-K=2 + reduce
        gemm128<<<dim3(8, 16, 2), 256, 0, stream>>>(
            ybf, D_INNER, owb, D_INNER,
            outp, nullptr, DIM, D_INNER / 2, op_psize);
        reduce2_k<<<(MROWS * DIM + 255) / 256, 256, 0, stream>>>(
            outp, op_psize, MROWS * DIM,
            (l == 1) ? out : nullptr, (l == 0) ? xmid : nullptr);
    }
}